// Round 5
// baseline (414.401 us; speedup 1.0000x reference)
//
#include <hip/hip_runtime.h>
#include <math.h>

// Problem constants (B=4, T=256, A=3, C=13, GRID=64, F=18, SCALE=4)
#define NTGT   1024                   // B*T
#define NCAND  (21 * NTGT)            // 7 offsets * 3 anchors * NTGT = 21504
#define NCBLK  (NCAND / 256)          // 84 candidate blocks
#define NCELL  (4 * 3 * 64 * 64 * 64) // B*A*GRID^3 = 3145728
#define BITW   (NCELL / 32)           // bitmap words = 98304
#define NBLK   2048
#define NF4    (NCELL * 18 / 4)       // 14,155,776 float4s in p
#define ITERS  (NF4 / (NBLK * 256))   // 27 float4s per thread, exact
#define BLKF4  (ITERS * 256)          // 6912 float4s per block (contiguous)
#define GRP    9                      // independent loads per batch (MLP)

// ws layout: acc[0]=nv, acc[1]=bbox, acc[2]=cls, acc[3]=softplus_sum,
//            acc[4]=claimed_p4_sum, [24]=u32 done-counter, [32..]=bitmap
__device__ __forceinline__ float softplusf(float x) {
    return fmaxf(x, 0.0f) + __logf(1.0f + __expf(-fabsf(x)));
}
__device__ __forceinline__ float sigmoidf(float x) {
    return 1.0f / (1.0f + __expf(-x));
}

__global__ __launch_bounds__(256) void fused_kernel(
    const float* __restrict__ p, const float* __restrict__ tg,
    const float* __restrict__ anchor, float* __restrict__ acc,
    unsigned int* __restrict__ ctr, unsigned int* __restrict__ bitmap,
    float* __restrict__ out)
{
    // ---- Part 1: candidate bbox/cls + occupancy claim (blocks 0..83) ----
    if (blockIdx.x < NCBLK) {
        int idx = blockIdx.x * 256 + threadIdx.x;
        float nv_v = 0.f, bb_v = 0.f, cl_v = 0.f, ob_v = 0.f;
        {
            int t  = idx & (NTGT - 1);   // target fastest -> coalesced tg reads
            int oa = idx >> 10;
            int a  = oa % 3;
            int o  = oa / 3;
            const float* x = tg + t * 18;
            float conf = x[4];
            float rn   = x[3] * 0.25f;           // r / SCALE
            float an   = anchor[a] * 0.25f;      // anchor_norm
            float ratio = rn / an;
            bool ok = (conf > 0.5f) && (fmaxf(ratio, 1.0f / ratio) < 4.0f);
            float gv[3] = { x[0] * 0.25f, x[1] * 0.25f, x[2] * 0.25f };
            float off[3] = { 0.f, 0.f, 0.f };
            if (o >= 1) {
                if (o <= 3) {               // m1: frac(g) < 0.5 && g > 1
                    int c = o - 1;
                    float v = gv[c];
                    ok = ok && ((v - floorf(v)) < 0.5f) && (v > 1.0f);
                    off[c] = 0.5f;
                } else {                    // m2: frac(64-g) < 0.5 && (64-g) > 1
                    int c = o - 4;
                    float vi = 64.0f - gv[c];
                    ok = ok && ((vi - floorf(vi)) < 0.5f) && (vi > 1.0f);
                    off[c] = -0.5f;
                }
            }
            if (ok) {
                float tb[3]; int gq[3];
                #pragma unroll
                for (int c = 0; c < 3; c++) {
                    float f = truncf(gv[c] - off[c]);
                    tb[c] = gv[c] - f;
                    gq[c] = min(max((int)f, 0), 63);
                }
                int b0 = t >> 8;             // T = 256
                unsigned int cell =
                    ((((unsigned)(b0 * 3 + a) * 64u + (unsigned)gq[2]) * 64u
                      + (unsigned)gq[1]) * 64u) + (unsigned)gq[0];
                const float* pp = p + (size_t)cell * 18u;

                float c1[3];
                #pragma unroll
                for (int c = 0; c < 3; c++) c1[c] = sigmoidf(pp[c]) * 2.0f - 0.5f;
                float s4 = sigmoidf(pp[3]) * 2.0f;
                float p4 = pp[4];
                float r1 = s4 * s4 * an;
                float r2 = rn;

                // EIOU
                float h1 = 0.5f * r1, h2 = 0.5f * r2;
                float inter = 1.f, rho2 = 0.f, c2d = 0.f, spen = 0.f;
                float dr2 = (r1 - r2) * (r1 - r2);
                #pragma unroll
                for (int c = 0; c < 3; c++) {
                    float lo1 = c1[c] - h1, hi1 = c1[c] + h1;
                    float lo2 = tb[c] - h2, hi2 = tb[c] + h2;
                    inter *= fmaxf(fminf(hi1, hi2) - fmaxf(lo1, lo2), 0.f);
                    float cd  = fmaxf(hi1, hi2) - fminf(lo1, lo2);
                    float cd2 = cd * cd;
                    float d   = c1[c] - tb[c];
                    rho2 += d * d;
                    c2d  += cd2;
                    spen += dr2 / (cd2 + 1e-7f);
                }
                float uni = r1 * r1 * r1 + r2 * r2 * r2 - inter + 1e-7f;
                float ei  = inter / uni - rho2 / (c2d + 1e-7f) - spen;

                nv_v = 1.0f;
                bb_v = 1.0f - ei;
                float cl = 0.f;
                #pragma unroll
                for (int c = 0; c < 13; c++) {   // bce(l,t)=sp(l)-t*l, t one-hot
                    float l = pp[5 + c];
                    cl += softplusf(l) - x[5 + c] * l;
                }
                cl_v = cl;
                // claim: first valid candidate on a cell contributes its p4 once
                unsigned int old = atomicOr(&bitmap[cell >> 5], 1u << (cell & 31u));
                if (!(old & (1u << (cell & 31u)))) ob_v = p4;
            }
        }
        #pragma unroll
        for (int s = 32; s > 0; s >>= 1) {
            nv_v += __shfl_down(nv_v, s, 64);
            bb_v += __shfl_down(bb_v, s, 64);
            cl_v += __shfl_down(cl_v, s, 64);
            ob_v += __shfl_down(ob_v, s, 64);
        }
        if ((threadIdx.x & 63) == 0 && nv_v != 0.f) {
            atomicAdd(&acc[0], nv_v);
            atomicAdd(&acc[1], bb_v);
            atomicAdd(&acc[2], cl_v);
            atomicAdd(&acc[4], ob_v);
        }
    }

    // ---- Part 2: stream ALL of p as coalesced float4; pick channel 4 by
    // residue arithmetic. float index f = 4*g, p4 <=> f mod 18 == 4; a float4
    // with leading residue r holds a p4 iff 1 <= r <= 4, at element (4 - r).
    // Batches of GRP=9 independent loads keep ~9 KB/wave in flight (MLP) --
    // unroll(3) at round 4 left ~2 loads in flight and ran at 1.3 TB/s.
    float s = 0.f;
    {
        const float4* p4v = (const float4*)p;
        int g0 = blockIdx.x * BLKF4 + threadIdx.x;      // first float4 index
        int r  = (4 * g0) % 18;                         // leading residue
        for (int grp = 0; grp < ITERS / GRP; grp++) {   // 3 groups
            float4 v[GRP];
            #pragma unroll
            for (int j = 0; j < GRP; j++) {
                v[j] = p4v[g0 + (grp * GRP + j) * 256]; // 9 independent loads
            }
            #pragma unroll
            for (int j = 0; j < GRP; j++) {
                if (r >= 1 && r <= 4) {
                    int k = 4 - r;                      // 0..3
                    float x = (k == 0) ? v[j].x : (k == 1) ? v[j].y
                            : (k == 2) ? v[j].z : v[j].w;
                    s += softplusf(x);
                }
                r += 16; if (r >= 18) r -= 18;
            }
        }
    }
    #pragma unroll
    for (int sh = 32; sh > 0; sh >>= 1) s += __shfl_down(s, sh, 64);
    __shared__ float sm[4];
    int lane = threadIdx.x & 63, w = threadIdx.x >> 6;
    if (lane == 0) sm[w] = s;
    __syncthreads();
    if (threadIdx.x == 0) {
        atomicAdd(&acc[3], sm[0] + sm[1] + sm[2] + sm[3]);
    }

    // ---- Part 3: last block combines scalars (no extra launch) ----
    __shared__ bool last;
    if (threadIdx.x == 0) {
        __threadfence();                         // order our atomics before ctr
        unsigned int prev = atomicAdd(ctr, 1u);
        last = (prev == NBLK - 1);
    }
    __syncthreads();
    if (last && threadIdx.x == 0) {
        float nv = fmaxf(atomicAdd(&acc[0], 0.f), 1.0f);
        float bb = atomicAdd(&acc[1], 0.f);
        float cl = atomicAdd(&acc[2], 0.f);
        float sp = atomicAdd(&acc[3], 0.f);
        float cp = atomicAdd(&acc[4], 0.f);
        float lb = bb / nv;                           // loss_bbox * 1.0
        float lc = cl / (nv * 13.0f) * 10.0f;         // loss_cls  * 10.0
        float lo = (sp - cp) * (20.0f / (float)NCELL);
        out[0] = (lb + lo + lc) * 4.0f;               // * Bs
        out[1] = lo;
        out[2] = lc;
    }
}

extern "C" void kernel_launch(void* const* d_in, const int* in_sizes, int n_in,
                              void* d_out, int out_size, void* d_ws, size_t ws_size,
                              hipStream_t stream) {
    const float* p       = (const float*)d_in[0];
    const float* targets = (const float*)d_in[1];
    const float* anchor  = (const float*)d_in[2];
    float* out = (float*)d_out;

    float* acc = (float*)d_ws;                                // 5 floats
    unsigned int* ctr    = (unsigned int*)((char*)d_ws + 24); // done-counter
    unsigned int* bitmap = (unsigned int*)((char*)d_ws + 32);

    // zero accumulators + counter + claim-bitmap
    hipMemsetAsync(d_ws, 0, 32 + (size_t)BITW * 4, stream);

    fused_kernel<<<NBLK, 256, 0, stream>>>(p, targets, anchor, acc, ctr,
                                           bitmap, out);
}

// Round 6
// 413.062 us; speedup vs baseline: 1.0032x; 1.0032x over previous
//
#include <hip/hip_runtime.h>
#include <math.h>

// Problem constants (B=4, T=256, A=3, C=13, GRID=64, F=18, SCALE=4)
#define NTGT   1024                   // B*T
#define NCAND  (21 * NTGT)            // 7 offsets * 3 anchors * NTGT = 21504
#define NCBLK  (NCAND / 256)          // 84 candidate blocks
#define NCELL  (4 * 3 * 64 * 64 * 64) // B*A*GRID^3 = 3145728
#define BITW   (NCELL / 32)           // bitmap words = 98304
#define NBLK   2048
#define NF4    (NCELL * 18 / 4)       // 14,155,776 float4s in p
#define ITERS  (NF4 / (NBLK * 256))   // 27 float4s per thread, exact
#define BLKF4  (ITERS * 256)          // 6912 float4s per block (contiguous)
#define GRP    9                      // forced-in-flight loads per batch

typedef float vf4 __attribute__((ext_vector_type(4)));

// ws layout: acc[0]=nv, acc[1]=bbox, acc[2]=cls, acc[3]=softplus_sum,
//            acc[4]=claimed_p4_sum, [24]=u32 done-counter, [32..]=bitmap
__device__ __forceinline__ float softplusf(float x) {
    return fmaxf(x, 0.0f) + __logf(1.0f + __expf(-fabsf(x)));
}
__device__ __forceinline__ float sigmoidf(float x) {
    return 1.0f / (1.0f + __expf(-x));
}

// ---- Kernel 1: candidate bbox/cls + occupancy claim (84 blocks) ----
__global__ __launch_bounds__(256) void cand_kernel(
    const float* __restrict__ p, const float* __restrict__ tg,
    const float* __restrict__ anchor, float* __restrict__ acc,
    unsigned int* __restrict__ bitmap)
{
    int idx = blockIdx.x * 256 + threadIdx.x;
    float nv_v = 0.f, bb_v = 0.f, cl_v = 0.f, ob_v = 0.f;
    {
        int t  = idx & (NTGT - 1);   // target fastest -> coalesced tg reads
        int oa = idx >> 10;
        int a  = oa % 3;
        int o  = oa / 3;
        const float* x = tg + t * 18;
        float conf = x[4];
        float rn   = x[3] * 0.25f;           // r / SCALE
        float an   = anchor[a] * 0.25f;      // anchor_norm
        float ratio = rn / an;
        bool ok = (conf > 0.5f) && (fmaxf(ratio, 1.0f / ratio) < 4.0f);
        float gv[3] = { x[0] * 0.25f, x[1] * 0.25f, x[2] * 0.25f };
        float off[3] = { 0.f, 0.f, 0.f };
        if (o >= 1) {
            if (o <= 3) {               // m1: frac(g) < 0.5 && g > 1
                int c = o - 1;
                float v = gv[c];
                ok = ok && ((v - floorf(v)) < 0.5f) && (v > 1.0f);
                off[c] = 0.5f;
            } else {                    // m2: frac(64-g) < 0.5 && (64-g) > 1
                int c = o - 4;
                float vi = 64.0f - gv[c];
                ok = ok && ((vi - floorf(vi)) < 0.5f) && (vi > 1.0f);
                off[c] = -0.5f;
            }
        }
        if (ok) {
            float tb[3]; int gq[3];
            #pragma unroll
            for (int c = 0; c < 3; c++) {
                float f = truncf(gv[c] - off[c]);
                tb[c] = gv[c] - f;
                gq[c] = min(max((int)f, 0), 63);
            }
            int b0 = t >> 8;             // T = 256
            unsigned int cell =
                ((((unsigned)(b0 * 3 + a) * 64u + (unsigned)gq[2]) * 64u
                  + (unsigned)gq[1]) * 64u) + (unsigned)gq[0];
            const float* pp = p + (size_t)cell * 18u;

            float c1[3];
            #pragma unroll
            for (int c = 0; c < 3; c++) c1[c] = sigmoidf(pp[c]) * 2.0f - 0.5f;
            float s4 = sigmoidf(pp[3]) * 2.0f;
            float p4 = pp[4];
            float r1 = s4 * s4 * an;
            float r2 = rn;

            // EIOU
            float h1 = 0.5f * r1, h2 = 0.5f * r2;
            float inter = 1.f, rho2 = 0.f, c2d = 0.f, spen = 0.f;
            float dr2 = (r1 - r2) * (r1 - r2);
            #pragma unroll
            for (int c = 0; c < 3; c++) {
                float lo1 = c1[c] - h1, hi1 = c1[c] + h1;
                float lo2 = tb[c] - h2, hi2 = tb[c] + h2;
                inter *= fmaxf(fminf(hi1, hi2) - fmaxf(lo1, lo2), 0.f);
                float cd  = fmaxf(hi1, hi2) - fminf(lo1, lo2);
                float cd2 = cd * cd;
                float d   = c1[c] - tb[c];
                rho2 += d * d;
                c2d  += cd2;
                spen += dr2 / (cd2 + 1e-7f);
            }
            float uni = r1 * r1 * r1 + r2 * r2 * r2 - inter + 1e-7f;
            float ei  = inter / uni - rho2 / (c2d + 1e-7f) - spen;

            nv_v = 1.0f;
            bb_v = 1.0f - ei;
            float cl = 0.f;
            #pragma unroll
            for (int c = 0; c < 13; c++) {   // bce(l,t)=sp(l)-t*l, t one-hot
                float l = pp[5 + c];
                cl += softplusf(l) - x[5 + c] * l;
            }
            cl_v = cl;
            // claim: first valid candidate on a cell contributes its p4 once
            unsigned int old = atomicOr(&bitmap[cell >> 5], 1u << (cell & 31u));
            if (!(old & (1u << (cell & 31u)))) ob_v = p4;
        }
    }
    #pragma unroll
    for (int s = 32; s > 0; s >>= 1) {
        nv_v += __shfl_down(nv_v, s, 64);
        bb_v += __shfl_down(bb_v, s, 64);
        cl_v += __shfl_down(cl_v, s, 64);
        ob_v += __shfl_down(ob_v, s, 64);
    }
    // block-level LDS reduce -> 4 atomics per block (not per wave)
    __shared__ float sm[4][4];
    int lane = threadIdx.x & 63, w = threadIdx.x >> 6;
    if (lane == 0) {
        sm[w][0] = nv_v; sm[w][1] = bb_v; sm[w][2] = cl_v; sm[w][3] = ob_v;
    }
    __syncthreads();
    if (threadIdx.x == 0) {
        float t0 = sm[0][0] + sm[1][0] + sm[2][0] + sm[3][0];
        float t1 = sm[0][1] + sm[1][1] + sm[2][1] + sm[3][1];
        float t2 = sm[0][2] + sm[1][2] + sm[2][2] + sm[3][2];
        float t3 = sm[0][3] + sm[1][3] + sm[2][3] + sm[3][3];
        if (t0 != 0.f) {
            atomicAdd(&acc[0], t0);
            atomicAdd(&acc[1], t1);
            atomicAdd(&acc[2], t2);
            atomicAdd(&acc[4], t3);
        }
    }
}

// ---- Kernel 2: stream all of p, softplus of channel 4 by residue; last
// block folds in the candidate sums and writes the output scalars. ----
// MLP is forced with inline asm: 9 global_load_dwordx4 held in flight per
// wave, one pinned s_waitcnt vmcnt(0) whose operands are all 9 quads, so
// the compiler can neither sink the loads nor hoist the consumers.
__global__ __launch_bounds__(256) void stream_kernel(
    const float* __restrict__ p, float* __restrict__ acc,
    unsigned int* __restrict__ ctr, float* __restrict__ out)
{
    float s = 0.f;
    {
        int g0 = blockIdx.x * BLKF4 + threadIdx.x;   // first float4 index
        unsigned int ob = (unsigned int)g0 * 16u;    // byte offset of it
        int r = (4 * g0) % 18;                       // leading residue
        for (int grp = 0; grp < ITERS / GRP; grp++) {   // 3 groups
            unsigned int gb = ob + (unsigned int)(grp * GRP * 4096);
            vf4 v0, v1, v2, v3, v4, v5, v6, v7, v8;
            asm volatile("global_load_dwordx4 %0, %1, %2" : "=v"(v0) : "v"(gb            ), "s"(p));
            asm volatile("global_load_dwordx4 %0, %1, %2" : "=v"(v1) : "v"(gb +  4096u), "s"(p));
            asm volatile("global_load_dwordx4 %0, %1, %2" : "=v"(v2) : "v"(gb +  8192u), "s"(p));
            asm volatile("global_load_dwordx4 %0, %1, %2" : "=v"(v3) : "v"(gb + 12288u), "s"(p));
            asm volatile("global_load_dwordx4 %0, %1, %2" : "=v"(v4) : "v"(gb + 16384u), "s"(p));
            asm volatile("global_load_dwordx4 %0, %1, %2" : "=v"(v5) : "v"(gb + 20480u), "s"(p));
            asm volatile("global_load_dwordx4 %0, %1, %2" : "=v"(v6) : "v"(gb + 24576u), "s"(p));
            asm volatile("global_load_dwordx4 %0, %1, %2" : "=v"(v7) : "v"(gb + 28672u), "s"(p));
            asm volatile("global_load_dwordx4 %0, %1, %2" : "=v"(v8) : "v"(gb + 32768u), "s"(p));
            asm volatile("s_waitcnt vmcnt(0)"
                         : "+v"(v0), "+v"(v1), "+v"(v2), "+v"(v3), "+v"(v4),
                           "+v"(v5), "+v"(v6), "+v"(v7), "+v"(v8));
            vf4 vv[GRP] = { v0, v1, v2, v3, v4, v5, v6, v7, v8 };
            #pragma unroll
            for (int j = 0; j < GRP; j++) {
                if (r >= 1 && r <= 4) {              // this float4 holds a p4
                    int k = 4 - r;                   // 0..3
                    float x = (k == 0) ? vv[j].x : (k == 1) ? vv[j].y
                            : (k == 2) ? vv[j].z : vv[j].w;
                    s += softplusf(x);
                }
                r += 16; if (r >= 18) r -= 18;       // residue -= 2 mod 18
            }
        }
    }
    #pragma unroll
    for (int sh = 32; sh > 0; sh >>= 1) s += __shfl_down(s, sh, 64);
    __shared__ float sm[4];
    int lane = threadIdx.x & 63, w = threadIdx.x >> 6;
    if (lane == 0) sm[w] = s;
    __syncthreads();
    if (threadIdx.x == 0) {
        atomicAdd(&acc[3], sm[0] + sm[1] + sm[2] + sm[3]);
    }

    // last block combines scalars (cand_kernel finished before we launched)
    __shared__ bool last;
    if (threadIdx.x == 0) {
        __threadfence();
        unsigned int prev = atomicAdd(ctr, 1u);
        last = (prev == NBLK - 1);
    }
    __syncthreads();
    if (last && threadIdx.x == 0) {
        float nv = fmaxf(atomicAdd(&acc[0], 0.f), 1.0f);
        float bb = atomicAdd(&acc[1], 0.f);
        float cl = atomicAdd(&acc[2], 0.f);
        float sp = atomicAdd(&acc[3], 0.f);
        float cp = atomicAdd(&acc[4], 0.f);
        float lb = bb / nv;                           // loss_bbox * 1.0
        float lc = cl / (nv * 13.0f) * 10.0f;         // loss_cls  * 10.0
        float lo = (sp - cp) * (20.0f / (float)NCELL);
        out[0] = (lb + lo + lc) * 4.0f;               // * Bs
        out[1] = lo;
        out[2] = lc;
    }
}

extern "C" void kernel_launch(void* const* d_in, const int* in_sizes, int n_in,
                              void* d_out, int out_size, void* d_ws, size_t ws_size,
                              hipStream_t stream) {
    const float* p       = (const float*)d_in[0];
    const float* targets = (const float*)d_in[1];
    const float* anchor  = (const float*)d_in[2];
    float* out = (float*)d_out;

    float* acc = (float*)d_ws;                                // 5 floats
    unsigned int* ctr    = (unsigned int*)((char*)d_ws + 24); // done-counter
    unsigned int* bitmap = (unsigned int*)((char*)d_ws + 32);

    // zero accumulators + counter + claim-bitmap
    hipMemsetAsync(d_ws, 0, 32 + (size_t)BITW * 4, stream);

    cand_kernel<<<NCBLK, 256, 0, stream>>>(p, targets, anchor, acc, bitmap);
    stream_kernel<<<NBLK, 256, 0, stream>>>(p, acc, ctr, out);
}

// Round 7
// 390.671 us; speedup vs baseline: 1.0607x; 1.0573x over previous
//
#include <hip/hip_runtime.h>
#include <math.h>

// Problem constants (B=4, T=256, A=3, C=13, GRID=64, F=18, SCALE=4)
#define NTGT   1024                   // B*T
#define NCAND  (21 * NTGT)            // 7 offsets * 3 anchors * NTGT = 21504
#define NCBLK  (NCAND / 256)          // 84 candidate blocks
#define NCELL  (4 * 3 * 64 * 64 * 64) // B*A*GRID^3 = 3145728
#define BITW   (NCELL / 32)           // bitmap words = 98304
#define NBLK   2048
#define NF4    (NCELL * 18 / 4)       // 14,155,776 float4s in p
#define ITERS  (NF4 / (NBLK * 256))   // 27 float4s per thread, exact
#define BLKF4  (ITERS * 256)          // 6912 float4s per block (contiguous)
#define GRP    9                      // in-flight loads per batch

typedef float vf4 __attribute__((ext_vector_type(4)));

// ws layout: acc[0]=nv, acc[1]=bbox, acc[2]=cls, acc[3]=softplus_sum,
//            acc[4]=claimed_p4_sum, [24]=u32 done-counter, [32..]=bitmap
__device__ __forceinline__ float softplusf(float x) {
    return fmaxf(x, 0.0f) + __logf(1.0f + __expf(-fabsf(x)));
}
__device__ __forceinline__ float sigmoidf(float x) {
    return 1.0f / (1.0f + __expf(-x));
}

// ---- Kernel 1: candidate bbox/cls + occupancy claim (84 blocks) ----
__global__ __launch_bounds__(256) void cand_kernel(
    const float* __restrict__ p, const float* __restrict__ tg,
    const float* __restrict__ anchor, float* __restrict__ acc,
    unsigned int* __restrict__ bitmap)
{
    int idx = blockIdx.x * 256 + threadIdx.x;
    float nv_v = 0.f, bb_v = 0.f, cl_v = 0.f, ob_v = 0.f;
    {
        int t  = idx & (NTGT - 1);   // target fastest -> coalesced tg reads
        int oa = idx >> 10;
        int a  = oa % 3;
        int o  = oa / 3;
        const float* x = tg + t * 18;
        float conf = x[4];
        float rn   = x[3] * 0.25f;           // r / SCALE
        float an   = anchor[a] * 0.25f;      // anchor_norm
        float ratio = rn / an;
        bool ok = (conf > 0.5f) && (fmaxf(ratio, 1.0f / ratio) < 4.0f);
        float gv[3] = { x[0] * 0.25f, x[1] * 0.25f, x[2] * 0.25f };
        float off[3] = { 0.f, 0.f, 0.f };
        if (o >= 1) {
            if (o <= 3) {               // m1: frac(g) < 0.5 && g > 1
                int c = o - 1;
                float v = gv[c];
                ok = ok && ((v - floorf(v)) < 0.5f) && (v > 1.0f);
                off[c] = 0.5f;
            } else {                    // m2: frac(64-g) < 0.5 && (64-g) > 1
                int c = o - 4;
                float vi = 64.0f - gv[c];
                ok = ok && ((vi - floorf(vi)) < 0.5f) && (vi > 1.0f);
                off[c] = -0.5f;
            }
        }
        if (ok) {
            float tb[3]; int gq[3];
            #pragma unroll
            for (int c = 0; c < 3; c++) {
                float f = truncf(gv[c] - off[c]);
                tb[c] = gv[c] - f;
                gq[c] = min(max((int)f, 0), 63);
            }
            int b0 = t >> 8;             // T = 256
            unsigned int cell =
                ((((unsigned)(b0 * 3 + a) * 64u + (unsigned)gq[2]) * 64u
                  + (unsigned)gq[1]) * 64u) + (unsigned)gq[0];
            const float* pp = p + (size_t)cell * 18u;

            float c1[3];
            #pragma unroll
            for (int c = 0; c < 3; c++) c1[c] = sigmoidf(pp[c]) * 2.0f - 0.5f;
            float s4 = sigmoidf(pp[3]) * 2.0f;
            float p4 = pp[4];
            float r1 = s4 * s4 * an;
            float r2 = rn;

            // EIOU
            float h1 = 0.5f * r1, h2 = 0.5f * r2;
            float inter = 1.f, rho2 = 0.f, c2d = 0.f, spen = 0.f;
            float dr2 = (r1 - r2) * (r1 - r2);
            #pragma unroll
            for (int c = 0; c < 3; c++) {
                float lo1 = c1[c] - h1, hi1 = c1[c] + h1;
                float lo2 = tb[c] - h2, hi2 = tb[c] + h2;
                inter *= fmaxf(fminf(hi1, hi2) - fmaxf(lo1, lo2), 0.f);
                float cd  = fmaxf(hi1, hi2) - fminf(lo1, lo2);
                float cd2 = cd * cd;
                float d   = c1[c] - tb[c];
                rho2 += d * d;
                c2d  += cd2;
                spen += dr2 / (cd2 + 1e-7f);
            }
            float uni = r1 * r1 * r1 + r2 * r2 * r2 - inter + 1e-7f;
            float ei  = inter / uni - rho2 / (c2d + 1e-7f) - spen;

            nv_v = 1.0f;
            bb_v = 1.0f - ei;
            float cl = 0.f;
            #pragma unroll
            for (int c = 0; c < 13; c++) {   // bce(l,t)=sp(l)-t*l, t one-hot
                float l = pp[5 + c];
                cl += softplusf(l) - x[5 + c] * l;
            }
            cl_v = cl;
            // claim: first valid candidate on a cell contributes its p4 once
            unsigned int old = atomicOr(&bitmap[cell >> 5], 1u << (cell & 31u));
            if (!(old & (1u << (cell & 31u)))) ob_v = p4;
        }
    }
    #pragma unroll
    for (int s = 32; s > 0; s >>= 1) {
        nv_v += __shfl_down(nv_v, s, 64);
        bb_v += __shfl_down(bb_v, s, 64);
        cl_v += __shfl_down(cl_v, s, 64);
        ob_v += __shfl_down(ob_v, s, 64);
    }
    // block-level LDS reduce -> 4 atomics per block
    __shared__ float sm[4][4];
    int lane = threadIdx.x & 63, w = threadIdx.x >> 6;
    if (lane == 0) {
        sm[w][0] = nv_v; sm[w][1] = bb_v; sm[w][2] = cl_v; sm[w][3] = ob_v;
    }
    __syncthreads();
    if (threadIdx.x == 0) {
        float t0 = sm[0][0] + sm[1][0] + sm[2][0] + sm[3][0];
        float t1 = sm[0][1] + sm[1][1] + sm[2][1] + sm[3][1];
        float t2 = sm[0][2] + sm[1][2] + sm[2][2] + sm[3][2];
        float t3 = sm[0][3] + sm[1][3] + sm[2][3] + sm[3][3];
        if (t0 != 0.f) {
            atomicAdd(&acc[0], t0);
            atomicAdd(&acc[1], t1);
            atomicAdd(&acc[2], t2);
            atomicAdd(&acc[4], t3);
        }
    }
}

// consume one float4 given current leading residue r (mod 18); p4 lives in a
// float4 iff 1 <= r <= 4, at element (4 - r). Then advance r by -2 mod 18.
#define CONSUME(v)                                                        \
    do {                                                                  \
        if (r >= 1 && r <= 4) {                                           \
            int k = 4 - r;                                                \
            float xx = (k == 0) ? (v).x : (k == 1) ? (v).y                \
                     : (k == 2) ? (v).z : (v).w;                          \
            s += softplusf(xx);                                           \
        }                                                                 \
        r += 16; if (r >= 18) r -= 18;                                    \
    } while (0)

// ---- Kernel 2: stream all of p (non-temporal float4), softplus of channel
// 4 by residue; last block folds in candidate sums and writes outputs. ----
// MLP: 9 NAMED vf4 temporaries per batch (no array -> no alloca -> the
// scheduler can keep all 9 global_load_dwordx4 nt in flight).
__global__ __launch_bounds__(256) void stream_kernel(
    const float* __restrict__ p, float* __restrict__ acc,
    unsigned int* __restrict__ ctr, float* __restrict__ out)
{
    float s = 0.f;
    {
        const vf4* p4v = (const vf4*)p;
        int g0 = blockIdx.x * BLKF4 + threadIdx.x;   // first float4 index
        int r  = (4 * g0) % 18;                      // leading residue
        for (int grp = 0; grp < ITERS / GRP; grp++) {   // 3 groups
            const vf4* b = p4v + g0 + grp * (GRP * 256);
            vf4 v0 = __builtin_nontemporal_load(b);
            vf4 v1 = __builtin_nontemporal_load(b + 1 * 256);
            vf4 v2 = __builtin_nontemporal_load(b + 2 * 256);
            vf4 v3 = __builtin_nontemporal_load(b + 3 * 256);
            vf4 v4 = __builtin_nontemporal_load(b + 4 * 256);
            vf4 v5 = __builtin_nontemporal_load(b + 5 * 256);
            vf4 v6 = __builtin_nontemporal_load(b + 6 * 256);
            vf4 v7 = __builtin_nontemporal_load(b + 7 * 256);
            vf4 v8 = __builtin_nontemporal_load(b + 8 * 256);
            CONSUME(v0); CONSUME(v1); CONSUME(v2);
            CONSUME(v3); CONSUME(v4); CONSUME(v5);
            CONSUME(v6); CONSUME(v7); CONSUME(v8);
        }
    }
    #pragma unroll
    for (int sh = 32; sh > 0; sh >>= 1) s += __shfl_down(s, sh, 64);
    __shared__ float sm[4];
    int lane = threadIdx.x & 63, w = threadIdx.x >> 6;
    if (lane == 0) sm[w] = s;
    __syncthreads();
    if (threadIdx.x == 0) {
        atomicAdd(&acc[3], sm[0] + sm[1] + sm[2] + sm[3]);
    }

    // last block combines scalars (cand_kernel completed before this kernel)
    __shared__ bool last;
    if (threadIdx.x == 0) {
        __threadfence();
        unsigned int prev = atomicAdd(ctr, 1u);
        last = (prev == NBLK - 1);
    }
    __syncthreads();
    if (last && threadIdx.x == 0) {
        float nv = fmaxf(atomicAdd(&acc[0], 0.f), 1.0f);
        float bb = atomicAdd(&acc[1], 0.f);
        float cl = atomicAdd(&acc[2], 0.f);
        float sp = atomicAdd(&acc[3], 0.f);
        float cp = atomicAdd(&acc[4], 0.f);
        float lb = bb / nv;                           // loss_bbox * 1.0
        float lc = cl / (nv * 13.0f) * 10.0f;         // loss_cls  * 10.0
        float lo = (sp - cp) * (20.0f / (float)NCELL);
        out[0] = (lb + lo + lc) * 4.0f;               // * Bs
        out[1] = lo;
        out[2] = lc;
    }
}

extern "C" void kernel_launch(void* const* d_in, const int* in_sizes, int n_in,
                              void* d_out, int out_size, void* d_ws, size_t ws_size,
                              hipStream_t stream) {
    const float* p       = (const float*)d_in[0];
    const float* targets = (const float*)d_in[1];
    const float* anchor  = (const float*)d_in[2];
    float* out = (float*)d_out;

    float* acc = (float*)d_ws;                                // 5 floats
    unsigned int* ctr    = (unsigned int*)((char*)d_ws + 24); // done-counter
    unsigned int* bitmap = (unsigned int*)((char*)d_ws + 32);

    // zero accumulators + counter + claim-bitmap
    hipMemsetAsync(d_ws, 0, 32 + (size_t)BITW * 4, stream);

    cand_kernel<<<NCBLK, 256, 0, stream>>>(p, targets, anchor, acc, bitmap);
    stream_kernel<<<NBLK, 256, 0, stream>>>(p, acc, ctr, out);
}